// Round 3
// baseline (781.766 us; speedup 1.0000x reference)
//
#include <hip/hip_runtime.h>
#include <hip/hip_bf16.h>

// graph_structure_learner round 3: MFMA MLP (K=160), 2-pass BN (recompute),
// B-frags direct from global (no W0 LDS stage -> 25KB LDS, 6 blocks/CU),
// no-max segment softmax fused into pass-2 epilogue (exp + atomic segsum).

#define SLOPE    0.01f
#define THRESH_C 1e-4f
#define BN_EPS_C 1e-5f

typedef __bf16 bf16x8 __attribute__((ext_vector_type(8)));
typedef float  f32x4  __attribute__((ext_vector_type(4)));

__device__ __forceinline__ unsigned short f2bf(float f) {
    unsigned u = __float_as_uint(f);
    unsigned r = u + 0x7fffu + ((u >> 16) & 1u);   // RNE
    return (unsigned short)(r >> 16);
}
__device__ __forceinline__ unsigned pk2(float a, float b) {
    return (unsigned)f2bf(a) | ((unsigned)f2bf(b) << 16);
}

// ---------------- init: zero stats + segsum + ori bitmap ----------------
__global__ void init_kernel(double* g_sum, double* g_sq, float* s,
                            unsigned* flags, int n_nodes, int nflag) {
    int idx = blockIdx.x * blockDim.x + threadIdx.x;
    if (idx < n_nodes) s[idx] = 0.f;
    if (idx < nflag)   flags[idx] = 0u;
    if (idx < 1024)    { g_sum[idx] = 0.0; g_sq[idx] = 0.0; }   // 8 replicas x 128
}

// ---------------- ori bitmap ----------------
__global__ void flag_kernel(const int* __restrict__ ori, unsigned* __restrict__ flags, int n_ori) {
    int i = blockIdx.x * blockDim.x + threadIdx.x;
    if (i < n_ori) { int e = ori[i]; atomicOr(&flags[e >> 5], 1u << (e & 31)); }
}

// ---------------- stats finalize: A = gamma*rstd, B = beta - mu*A ----------------
__global__ void stats_kernel(const double* __restrict__ g_sum, const double* __restrict__ g_sq,
                             const float* __restrict__ gamma, const float* __restrict__ beta,
                             float* __restrict__ AB, int E) {
    int j = threadIdx.x;
    if (j < 128) {
        double s = 0.0, q = 0.0;
#pragma unroll
        for (int r = 0; r < 8; r++) { s += g_sum[r * 128 + j]; q += g_sq[r * 128 + j]; }
        double mu  = s / (double)E;
        double var = q / (double)E - mu * mu;
        double rstd = 1.0 / sqrt(var + (double)BN_EPS_C);
        float A = (float)rstd * gamma[j];
        AB[j]       = A;
        AB[128 + j] = beta[j] - (float)mu * A;
    }
}

// ---------------- main pass: MODE 0 = stats, MODE 1 = e=exp(w) + segsum ----------------
// 64-edge tiles; A = [sim | rel] bf16 in LDS (row stride 384 B, XOR-swizzled);
// B = W0^T (160x128) bf16 in registers, loaded directly from global (coalesced).
template <int MODE>
__global__ __launch_bounds__(256, 6) void pass_kernel(
    const float* __restrict__ n_feat, const float* __restrict__ W0,
    const float* __restrict__ rel, const float* __restrict__ b0,
    const int* __restrict__ row, const int* __restrict__ col,
    const int* __restrict__ etype, const float* __restrict__ AB,
    const float* __restrict__ W1, const float* __restrict__ b1,
    double* __restrict__ g_sum, double* __restrict__ g_sq,
    const unsigned* __restrict__ flags, float* __restrict__ segsum,
    float* __restrict__ out_e, int E, int ntiles)
{
    __shared__ __align__(16) char lds[25600];   // A-tile 24576 B + wsum 1024 B

    const int tid  = threadIdx.x;
    const int lane = tid & 63;
    const int wv   = tid >> 6;
    const int grp  = lane >> 4;
    const int l15  = lane & 15;

    // ---- B fragments straight from global W0 (lane -> col => coalesced) ----
    bf16x8 bf[2][5];
#pragma unroll
    for (int ct = 0; ct < 2; ct++) {
        const int bcol = wv * 32 + ct * 16 + l15;
#pragma unroll
        for (int ks = 0; ks < 5; ks++) {
            const int k0 = ks * 32 + grp * 8;
#pragma unroll
            for (int j = 0; j < 8; j++)
                bf[ct][ks][j] = (__bf16)W0[(size_t)(k0 + j) * 128 + bcol];
        }
    }

    float b0v[2], A0v[2] = {0, 0}, B0v[2] = {0, 0}, W1v[2] = {0, 0}, b1v = 0.f;
#pragma unroll
    for (int ct = 0; ct < 2; ct++) {
        int c = wv * 32 + ct * 16 + l15;
        b0v[ct] = b0[c];
        if (MODE == 1) { A0v[ct] = AB[c]; B0v[ct] = AB[128 + c]; W1v[ct] = W1[c]; }
    }
    if (MODE == 1) b1v = b1[0];

    float sums[2] = {0, 0}, sqs[2] = {0, 0};

    char*  Ab   = lds;                        // 64 rows x 384 B
    float* wsum = (float*)(lds + 24576);      // [4][64]

    const float4* nf4 = (const float4*)n_feat;
    const int e_loc = tid >> 2, q = tid & 3;
    char* wr_base = Ab + e_loc * 384;
    const unsigned sw = (unsigned)(e_loc & 7) << 4;

    int prev_base = 0; bool have_prev = false;

    for (int t = blockIdx.x; t < ntiles; t += gridDim.x) {
        const int ebase = t << 6;

        // -------- stage: sim=exp(-|src-dst|) + rel, bf16, swizzled --------
        {
            const int eid = ebase + e_loc;
            unsigned simw[16], relw[4];
            if (eid < E) {
                const int r = row[eid], c = col[eid], ty = etype[eid];
                const float4* ra = nf4 + (size_t)r * 32 + q * 8;
                const float4* rb = nf4 + (size_t)c * 32 + q * 8;
#pragma unroll
                for (int i = 0; i < 8; i++) {
                    float4 a = ra[i], b = rb[i];
                    float s0 = __expf(-fabsf(a.x - b.x));
                    float s1 = __expf(-fabsf(a.y - b.y));
                    float s2 = __expf(-fabsf(a.z - b.z));
                    float s3 = __expf(-fabsf(a.w - b.w));
                    simw[2 * i]     = pk2(s0, s1);
                    simw[2 * i + 1] = pk2(s2, s3);
                }
                const float4* rr = (const float4*)(rel + (size_t)ty * 32 + q * 8);
                float4 r0 = rr[0], r1 = rr[1];
                relw[0] = pk2(r0.x, r0.y); relw[1] = pk2(r0.z, r0.w);
                relw[2] = pk2(r1.x, r1.y); relw[3] = pk2(r1.z, r1.w);
            } else {
#pragma unroll
                for (int i = 0; i < 16; i++) simw[i] = 0u;
                relw[0] = relw[1] = relw[2] = relw[3] = 0u;
            }
#pragma unroll
            for (int wq = 0; wq < 4; wq++)
                *(uint4*)(wr_base + (((unsigned)(q * 64 + wq * 16)) ^ sw)) =
                    make_uint4(simw[4 * wq], simw[4 * wq + 1], simw[4 * wq + 2], simw[4 * wq + 3]);
            *(uint4*)(wr_base + (((unsigned)(256 + q * 16)) ^ sw)) =
                make_uint4(relw[0], relw[1], relw[2], relw[3]);
        }

        // combine previous tile's per-wave partials -> w -> blend -> exp -> segsum
        if (MODE == 1 && have_prev && tid < 64) {
            int e = prev_base + tid;
            if (e < E) {
                float w = wsum[tid] + wsum[64 + tid] + wsum[128 + tid] + wsum[192 + tid] + b1v;
                if ((flags[e >> 5] >> (e & 31)) & 1u) w = fmaf(w, 0.5f, 0.5f);
                float ev = __expf(w);
                out_e[e] = ev;
                atomicAdd(&segsum[col[e]], ev);
            }
        }
        __syncthreads();

        // -------- compute: h = [sim|rel] @ W0 + b0 via MFMA --------
        f32x4 acc[4][2];
#pragma unroll
        for (int rt = 0; rt < 4; rt++)
#pragma unroll
            for (int ct = 0; ct < 2; ct++)
                acc[rt][ct] = {b0v[ct], b0v[ct], b0v[ct], b0v[ct]};

#pragma unroll
        for (int rt = 0; rt < 4; rt++) {
            const int arow = rt * 16 + l15;
            const char* rbp = Ab + arow * 384;
            const unsigned asw = (unsigned)(arow & 7) << 4;
            bf16x8 a[5];
#pragma unroll
            for (int ks = 0; ks < 5; ks++)
                a[ks] = *(const bf16x8*)(rbp + (((unsigned)(ks * 64 + grp * 16)) ^ asw));
#pragma unroll
            for (int ct = 0; ct < 2; ct++)
#pragma unroll
                for (int ks = 0; ks < 5; ks++)
                    acc[rt][ct] = __builtin_amdgcn_mfma_f32_16x16x32_bf16(
                        a[ks], bf[ct][ks], acc[rt][ct], 0, 0, 0);
        }

        if (MODE == 0) {
            if (ebase + 64 <= E) {
#pragma unroll
                for (int rt = 0; rt < 4; rt++)
#pragma unroll
                    for (int ct = 0; ct < 2; ct++) {
                        f32x4 h = acc[rt][ct];
#pragma unroll
                        for (int rg = 0; rg < 4; rg++) {
                            sums[ct] += h[rg];
                            sqs[ct]  = fmaf(h[rg], h[rg], sqs[ct]);
                        }
                    }
            } else {
#pragma unroll
                for (int rt = 0; rt < 4; rt++)
#pragma unroll
                    for (int rg = 0; rg < 4; rg++) {
                        int eid = ebase + rt * 16 + grp * 4 + rg;
                        float m = (eid < E) ? 1.f : 0.f;
#pragma unroll
                        for (int ct = 0; ct < 2; ct++) {
                            float h = acc[rt][ct][rg] * m;
                            sums[ct] += h;
                            sqs[ct]  = fmaf(h, h, sqs[ct]);
                        }
                    }
            }
        } else {
            // epilogue: BN affine -> LeakyReLU -> *W1 -> col-reduce -> wsum
#pragma unroll
            for (int rt = 0; rt < 4; rt++) {
#pragma unroll
                for (int rg = 0; rg < 4; rg++) {
                    float v = 0.f;
#pragma unroll
                    for (int ct = 0; ct < 2; ct++) {
                        float h = fmaf(acc[rt][ct][rg], A0v[ct], B0v[ct]);
                        h = h >= 0.f ? h : SLOPE * h;
                        v = fmaf(h, W1v[ct], v);
                    }
                    v += __shfl_xor(v, 1); v += __shfl_xor(v, 2);
                    v += __shfl_xor(v, 4); v += __shfl_xor(v, 8);
                    if (l15 == 0) wsum[wv * 64 + rt * 16 + grp * 4 + rg] = v;
                }
            }
            prev_base = ebase; have_prev = true;
        }
        __syncthreads();
    }

    if (MODE == 1 && have_prev && tid < 64) {
        int e = prev_base + tid;
        if (e < E) {
            float w = wsum[tid] + wsum[64 + tid] + wsum[128 + tid] + wsum[192 + tid] + b1v;
            if ((flags[e >> 5] >> (e & 31)) & 1u) w = fmaf(w, 0.5f, 0.5f);
            float ev = __expf(w);
            out_e[e] = ev;
            atomicAdd(&segsum[col[e]], ev);
        }
    }

    if (MODE == 0) {
#pragma unroll
        for (int ct = 0; ct < 2; ct++) {
            sums[ct] += __shfl_xor(sums[ct], 16); sums[ct] += __shfl_xor(sums[ct], 32);
            sqs[ct]  += __shfl_xor(sqs[ct], 16);  sqs[ct]  += __shfl_xor(sqs[ct], 32);
        }
        if (lane < 16) {
            int rep = blockIdx.x & 7;
#pragma unroll
            for (int ct = 0; ct < 2; ct++) {
                int c = wv * 32 + ct * 16 + lane;
                atomicAdd(&g_sum[rep * 128 + c], (double)sums[ct]);
                atomicAdd(&g_sq[rep * 128 + c], (double)sqs[ct]);
            }
        }
    }
}

// ---------------- normalize + threshold ----------------
__global__ void norm_kernel(const int* __restrict__ col, const float* __restrict__ s,
                            float* __restrict__ out, int E) {
    int i = blockIdx.x * blockDim.x + threadIdx.x;
    if (i < E) {
        float v = out[i] / s[col[i]];
        out[i] = v > THRESH_C ? v : 0.f;
    }
}

extern "C" void kernel_launch(void* const* d_in, const int* in_sizes, int n_in,
                              void* d_out, int out_size, void* d_ws, size_t ws_size,
                              hipStream_t stream) {
    const float* n_feat = (const float*)d_in[0];
    const float* rel    = (const float*)d_in[1];
    const float* W0     = (const float*)d_in[2];
    const float* b0     = (const float*)d_in[3];
    const float* gamma  = (const float*)d_in[4];
    const float* beta   = (const float*)d_in[5];
    const float* W1     = (const float*)d_in[6];
    const float* b1     = (const float*)d_in[7];
    const int*   row    = (const int*)d_in[8];
    const int*   col    = (const int*)d_in[9];
    const int*   etype  = (const int*)d_in[10];
    const int*   ori    = (const int*)d_in[11];

    const int E    = in_sizes[8];
    const int Nn   = in_sizes[0] / 128;
    const int nOri = in_sizes[11];
    const int nflag = (E + 31) / 32;
    float* out = (float*)d_out;

    char* ws = (char*)d_ws;
    double*   g_sum = (double*)(ws + 0);          // 8 x 128 doubles
    double*   g_sq  = (double*)(ws + 8192);       // 8 x 128 doubles
    float*    AB    = (float*)(ws + 16384);       // 256 f32
    unsigned* flags = (unsigned*)(ws + 17408);    // E/32 words
    float*    sbuf  = (float*)(ws + 17408 + 4 * (size_t)nflag);

    int nbN = ((Nn > 1024 ? Nn : 1024) + 255) / 256;
    init_kernel<<<nbN, 256, 0, stream>>>(g_sum, g_sq, sbuf, flags, Nn, nflag);

    int nbO = (nOri + 255) / 256;
    flag_kernel<<<nbO, 256, 0, stream>>>(ori, flags, nOri);

    const int ntiles = (E + 63) >> 6;
    const int grid_p = ntiles < 1536 ? ntiles : 1536;

    pass_kernel<0><<<grid_p, 256, 0, stream>>>(n_feat, W0, rel, b0, row, col, etype,
                                               AB, W1, b1, g_sum, g_sq, flags, sbuf, out, E, ntiles);

    stats_kernel<<<1, 128, 0, stream>>>(g_sum, g_sq, gamma, beta, AB, E);

    pass_kernel<1><<<grid_p, 256, 0, stream>>>(n_feat, W0, rel, b0, row, col, etype,
                                               AB, W1, b1, g_sum, g_sq, flags, sbuf, out, E, ntiles);

    int nbE = (E + 255) / 256;
    norm_kernel<<<nbE, 256, 0, stream>>>(col, sbuf, out, E);
}

// Round 4
// 320.011 us; speedup vs baseline: 2.4429x; 2.4429x over previous
//
#include <hip/hip_runtime.h>
#include <hip/hip_bf16.h>

// graph_structure_learner round 4: MFMA MLP (K=160), BN stats pass stores h
// (bf16, MFMA-lane order) to workspace when ws_size permits; pass 2 is then a
// thin BW-bound epilogue sweep (no re-gather). Fallback: recompute path.
// launch_bounds(256,4) — round 3's (256,6) caused a VGPR spill catastrophe.

#define SLOPE    0.01f
#define THRESH_C 1e-4f
#define BN_EPS_C 1e-5f

typedef __bf16 bf16x8 __attribute__((ext_vector_type(8)));
typedef float  f32x4  __attribute__((ext_vector_type(4)));

__device__ __forceinline__ unsigned short f2bf(float f) {
    unsigned u = __float_as_uint(f);
    unsigned r = u + 0x7fffu + ((u >> 16) & 1u);   // RNE
    return (unsigned short)(r >> 16);
}
__device__ __forceinline__ unsigned pk2(float a, float b) {
    return (unsigned)f2bf(a) | ((unsigned)f2bf(b) << 16);
}
__device__ __forceinline__ float lo16(unsigned u) { return __uint_as_float(u << 16); }
__device__ __forceinline__ float hi16(unsigned u) { return __uint_as_float(u & 0xffff0000u); }

// ---------------- init: zero stats + segsum + ori bitmap ----------------
__global__ void init_kernel(double* g_sum, double* g_sq, float* s,
                            unsigned* flags, int n_nodes, int nflag) {
    int idx = blockIdx.x * blockDim.x + threadIdx.x;
    if (idx < n_nodes) s[idx] = 0.f;
    if (idx < nflag)   flags[idx] = 0u;
    if (idx < 1024)    { g_sum[idx] = 0.0; g_sq[idx] = 0.0; }   // 8 replicas x 128
}

// ---------------- ori bitmap ----------------
__global__ void flag_kernel(const int* __restrict__ ori, unsigned* __restrict__ flags, int n_ori) {
    int i = blockIdx.x * blockDim.x + threadIdx.x;
    if (i < n_ori) { int e = ori[i]; atomicOr(&flags[e >> 5], 1u << (e & 31)); }
}

// ---------------- stats finalize: A = gamma*rstd, B = beta - mu*A ----------------
__global__ void stats_kernel(const double* __restrict__ g_sum, const double* __restrict__ g_sq,
                             const float* __restrict__ gamma, const float* __restrict__ beta,
                             float* __restrict__ AB, int E) {
    int j = threadIdx.x;
    if (j < 128) {
        double s = 0.0, q = 0.0;
#pragma unroll
        for (int r = 0; r < 8; r++) { s += g_sum[r * 128 + j]; q += g_sq[r * 128 + j]; }
        double mu  = s / (double)E;
        double var = q / (double)E - mu * mu;
        double rstd = 1.0 / sqrt(var + (double)BN_EPS_C);
        float A = (float)rstd * gamma[j];
        AB[j]       = A;
        AB[128 + j] = beta[j] - (float)mu * A;
    }
}

// MODE 0: stats only (recompute fallback pass 1)
// MODE 1: stats + store h bf16 to hbuf
// MODE 2: w-pass, recompute h (fallback pass 2)
// MODE 3: w-pass, read h from hbuf (thin epilogue sweep)
template <int MODE>
__global__ __launch_bounds__(256, 4) void pass_kernel(
    const float* __restrict__ n_feat, const float* __restrict__ W0,
    const float* __restrict__ rel, const float* __restrict__ b0,
    const int* __restrict__ row, const int* __restrict__ col,
    const int* __restrict__ etype, const float* __restrict__ AB,
    const float* __restrict__ W1, const float* __restrict__ b1,
    double* __restrict__ g_sum, double* __restrict__ g_sq,
    const unsigned* __restrict__ flags, float* __restrict__ segsum,
    float* __restrict__ out_e, unsigned* __restrict__ hbuf, int E, int ntiles)
{
    __shared__ __align__(16) char lds[25600];   // A-tile 24576 B + wsum 1024 B

    const int tid  = threadIdx.x;
    const int lane = tid & 63;
    const int wv   = tid >> 6;
    const int grp  = lane >> 4;
    const int l15  = lane & 15;

    if (MODE == 3) {
        // ---- thin epilogue: read h (same lane order as writer), no gather ----
        float* wsum = (float*)lds;
        float A0v[2], B0v[2], W1v[2];
#pragma unroll
        for (int ct = 0; ct < 2; ct++) {
            int c = wv * 32 + ct * 16 + l15;
            A0v[ct] = AB[c]; B0v[ct] = AB[128 + c]; W1v[ct] = W1[c];
        }
        const float b1v = b1[0];
        for (int t = blockIdx.x; t < ntiles; t += gridDim.x) {
            const int ebase = t << 6;
            const unsigned* hp = hbuf + (size_t)t * 4096;
            unsigned hw[16];
#pragma unroll
            for (int j = 0; j < 16; j++) hw[j] = hp[j * 256 + tid];
#pragma unroll
            for (int rt = 0; rt < 4; rt++) {
                float v[4] = {0.f, 0.f, 0.f, 0.f};
#pragma unroll
                for (int ct = 0; ct < 2; ct++) {
                    unsigned u0 = hw[rt * 4 + ct * 2], u1 = hw[rt * 4 + ct * 2 + 1];
                    float hv[4] = {lo16(u0), hi16(u0), lo16(u1), hi16(u1)};
#pragma unroll
                    for (int rg = 0; rg < 4; rg++) {
                        float h = fmaf(hv[rg], A0v[ct], B0v[ct]);
                        h = h >= 0.f ? h : SLOPE * h;
                        v[rg] = fmaf(h, W1v[ct], v[rg]);
                    }
                }
#pragma unroll
                for (int rg = 0; rg < 4; rg++) {
                    float x = v[rg];
                    x += __shfl_xor(x, 1); x += __shfl_xor(x, 2);
                    x += __shfl_xor(x, 4); x += __shfl_xor(x, 8);
                    if (l15 == 0) wsum[wv * 64 + rt * 16 + grp * 4 + rg] = x;
                }
            }
            __syncthreads();
            if (tid < 64) {
                int e = ebase + tid;
                if (e < E) {
                    float w = wsum[tid] + wsum[64 + tid] + wsum[128 + tid] + wsum[192 + tid] + b1v;
                    if ((flags[e >> 5] >> (e & 31)) & 1u) w = fmaf(w, 0.5f, 0.5f);
                    float ev = __expf(w);
                    out_e[e] = ev;
                    atomicAdd(&segsum[col[e]], ev);
                }
            }
            __syncthreads();
        }
        return;
    }

    // ---- B fragments straight from global W0 (lane -> col => coalesced) ----
    bf16x8 bf[2][5];
#pragma unroll
    for (int ct = 0; ct < 2; ct++) {
        const int bcol = wv * 32 + ct * 16 + l15;
#pragma unroll
        for (int ks = 0; ks < 5; ks++) {
            const int k0 = ks * 32 + grp * 8;
#pragma unroll
            for (int j = 0; j < 8; j++)
                bf[ct][ks][j] = (__bf16)W0[(size_t)(k0 + j) * 128 + bcol];
        }
    }

    float b0v[2], A0v[2] = {0, 0}, B0v[2] = {0, 0}, W1v[2] = {0, 0}, b1v = 0.f;
#pragma unroll
    for (int ct = 0; ct < 2; ct++) {
        int c = wv * 32 + ct * 16 + l15;
        b0v[ct] = b0[c];
        if (MODE == 2) { A0v[ct] = AB[c]; B0v[ct] = AB[128 + c]; W1v[ct] = W1[c]; }
    }
    if (MODE == 2) b1v = b1[0];

    float sums[2] = {0, 0}, sqs[2] = {0, 0};

    char*  Ab   = lds;                        // 64 rows x 384 B
    float* wsum = (float*)(lds + 24576);      // [4][64]

    const float4* nf4 = (const float4*)n_feat;
    const int e_loc = tid >> 2, q = tid & 3;
    char* wr_base = Ab + e_loc * 384;
    const unsigned sw = (unsigned)(e_loc & 7) << 4;

    int prev_base = 0; bool have_prev = false;

    for (int t = blockIdx.x; t < ntiles; t += gridDim.x) {
        const int ebase = t << 6;

        // -------- stage: sim=exp(-|src-dst|) + rel, bf16, swizzled --------
        {
            const int eid = ebase + e_loc;
            unsigned simw[16], relw[4];
            if (eid < E) {
                const int r = row[eid], c = col[eid], ty = etype[eid];
                const float4* ra = nf4 + (size_t)r * 32 + q * 8;
                const float4* rb = nf4 + (size_t)c * 32 + q * 8;
#pragma unroll
                for (int i = 0; i < 8; i++) {
                    float4 a = ra[i], b = rb[i];
                    float s0 = __expf(-fabsf(a.x - b.x));
                    float s1 = __expf(-fabsf(a.y - b.y));
                    float s2 = __expf(-fabsf(a.z - b.z));
                    float s3 = __expf(-fabsf(a.w - b.w));
                    simw[2 * i]     = pk2(s0, s1);
                    simw[2 * i + 1] = pk2(s2, s3);
                }
                const float4* rr = (const float4*)(rel + (size_t)ty * 32 + q * 8);
                float4 r0 = rr[0], r1 = rr[1];
                relw[0] = pk2(r0.x, r0.y); relw[1] = pk2(r0.z, r0.w);
                relw[2] = pk2(r1.x, r1.y); relw[3] = pk2(r1.z, r1.w);
            } else {
#pragma unroll
                for (int i = 0; i < 16; i++) simw[i] = 0u;
                relw[0] = relw[1] = relw[2] = relw[3] = 0u;
            }
#pragma unroll
            for (int wq = 0; wq < 4; wq++)
                *(uint4*)(wr_base + (((unsigned)(q * 64 + wq * 16)) ^ sw)) =
                    make_uint4(simw[4 * wq], simw[4 * wq + 1], simw[4 * wq + 2], simw[4 * wq + 3]);
            *(uint4*)(wr_base + (((unsigned)(256 + q * 16)) ^ sw)) =
                make_uint4(relw[0], relw[1], relw[2], relw[3]);
        }

        // combine previous tile's per-wave partials -> w -> blend -> exp -> segsum
        if (MODE == 2 && have_prev && tid < 64) {
            int e = prev_base + tid;
            if (e < E) {
                float w = wsum[tid] + wsum[64 + tid] + wsum[128 + tid] + wsum[192 + tid] + b1v;
                if ((flags[e >> 5] >> (e & 31)) & 1u) w = fmaf(w, 0.5f, 0.5f);
                float ev = __expf(w);
                out_e[e] = ev;
                atomicAdd(&segsum[col[e]], ev);
            }
        }
        __syncthreads();

        // -------- compute: h = [sim|rel] @ W0 + b0 via MFMA --------
        f32x4 acc[4][2];
#pragma unroll
        for (int rt = 0; rt < 4; rt++)
#pragma unroll
            for (int ct = 0; ct < 2; ct++)
                acc[rt][ct] = {b0v[ct], b0v[ct], b0v[ct], b0v[ct]};

#pragma unroll
        for (int rt = 0; rt < 4; rt++) {
            const int arow = rt * 16 + l15;
            const char* rbp = Ab + arow * 384;
            const unsigned asw = (unsigned)(arow & 7) << 4;
            bf16x8 a[5];
#pragma unroll
            for (int ks = 0; ks < 5; ks++)
                a[ks] = *(const bf16x8*)(rbp + (((unsigned)(ks * 64 + grp * 16)) ^ asw));
#pragma unroll
            for (int ct = 0; ct < 2; ct++)
#pragma unroll
                for (int ks = 0; ks < 5; ks++)
                    acc[rt][ct] = __builtin_amdgcn_mfma_f32_16x16x32_bf16(
                        a[ks], bf[ct][ks], acc[rt][ct], 0, 0, 0);
        }

        if (MODE == 1) {
            unsigned* hp = hbuf + (size_t)t * 4096;
#pragma unroll
            for (int rt = 0; rt < 4; rt++)
#pragma unroll
                for (int ct = 0; ct < 2; ct++) {
                    hp[(rt * 4 + ct * 2 + 0) * 256 + tid] = pk2(acc[rt][ct][0], acc[rt][ct][1]);
                    hp[(rt * 4 + ct * 2 + 1) * 256 + tid] = pk2(acc[rt][ct][2], acc[rt][ct][3]);
                }
        }

        if (MODE <= 1) {
            if (ebase + 64 <= E) {
#pragma unroll
                for (int rt = 0; rt < 4; rt++)
#pragma unroll
                    for (int ct = 0; ct < 2; ct++) {
                        f32x4 h = acc[rt][ct];
#pragma unroll
                        for (int rg = 0; rg < 4; rg++) {
                            sums[ct] += h[rg];
                            sqs[ct]  = fmaf(h[rg], h[rg], sqs[ct]);
                        }
                    }
            } else {
#pragma unroll
                for (int rt = 0; rt < 4; rt++)
#pragma unroll
                    for (int rg = 0; rg < 4; rg++) {
                        int eid = ebase + rt * 16 + grp * 4 + rg;
                        float m = (eid < E) ? 1.f : 0.f;
#pragma unroll
                        for (int ct = 0; ct < 2; ct++) {
                            float h = acc[rt][ct][rg] * m;
                            sums[ct] += h;
                            sqs[ct]  = fmaf(h, h, sqs[ct]);
                        }
                    }
            }
        } else {
            // epilogue: BN affine -> LeakyReLU -> *W1 -> col-reduce -> wsum
#pragma unroll
            for (int rt = 0; rt < 4; rt++) {
#pragma unroll
                for (int rg = 0; rg < 4; rg++) {
                    float v = 0.f;
#pragma unroll
                    for (int ct = 0; ct < 2; ct++) {
                        float h = fmaf(acc[rt][ct][rg], A0v[ct], B0v[ct]);
                        h = h >= 0.f ? h : SLOPE * h;
                        v = fmaf(h, W1v[ct], v);
                    }
                    v += __shfl_xor(v, 1); v += __shfl_xor(v, 2);
                    v += __shfl_xor(v, 4); v += __shfl_xor(v, 8);
                    if (l15 == 0) wsum[wv * 64 + rt * 16 + grp * 4 + rg] = v;
                }
            }
            prev_base = ebase; have_prev = true;
        }
        __syncthreads();
    }

    if (MODE == 2 && have_prev && tid < 64) {
        int e = prev_base + tid;
        if (e < E) {
            float w = wsum[tid] + wsum[64 + tid] + wsum[128 + tid] + wsum[192 + tid] + b1v;
            if ((flags[e >> 5] >> (e & 31)) & 1u) w = fmaf(w, 0.5f, 0.5f);
            float ev = __expf(w);
            out_e[e] = ev;
            atomicAdd(&segsum[col[e]], ev);
        }
    }

    if (MODE <= 1) {
#pragma unroll
        for (int ct = 0; ct < 2; ct++) {
            sums[ct] += __shfl_xor(sums[ct], 16); sums[ct] += __shfl_xor(sums[ct], 32);
            sqs[ct]  += __shfl_xor(sqs[ct], 16);  sqs[ct]  += __shfl_xor(sqs[ct], 32);
        }
        if (lane < 16) {
            int rep = blockIdx.x & 7;
#pragma unroll
            for (int ct = 0; ct < 2; ct++) {
                int c = wv * 32 + ct * 16 + lane;
                atomicAdd(&g_sum[rep * 128 + c], (double)sums[ct]);
                atomicAdd(&g_sq[rep * 128 + c], (double)sqs[ct]);
            }
        }
    }
}

// ---------------- normalize + threshold ----------------
__global__ void norm_kernel(const int* __restrict__ col, const float* __restrict__ s,
                            float* __restrict__ out, int E) {
    int i = blockIdx.x * blockDim.x + threadIdx.x;
    if (i < E) {
        float v = out[i] / s[col[i]];
        out[i] = v > THRESH_C ? v : 0.f;
    }
}

extern "C" void kernel_launch(void* const* d_in, const int* in_sizes, int n_in,
                              void* d_out, int out_size, void* d_ws, size_t ws_size,
                              hipStream_t stream) {
    const float* n_feat = (const float*)d_in[0];
    const float* rel    = (const float*)d_in[1];
    const float* W0     = (const float*)d_in[2];
    const float* b0     = (const float*)d_in[3];
    const float* gamma  = (const float*)d_in[4];
    const float* beta   = (const float*)d_in[5];
    const float* W1     = (const float*)d_in[6];
    const float* b1     = (const float*)d_in[7];
    const int*   row    = (const int*)d_in[8];
    const int*   col    = (const int*)d_in[9];
    const int*   etype  = (const int*)d_in[10];
    const int*   ori    = (const int*)d_in[11];

    const int E     = in_sizes[8];
    const int Nn    = in_sizes[0] / 128;
    const int nOri  = in_sizes[11];
    const int nflag = (E + 31) / 32;
    const int ntiles = (E + 63) >> 6;
    float* out = (float*)d_out;

    char* ws = (char*)d_ws;
    double*   g_sum = (double*)(ws + 0);          // 8 x 128 doubles
    double*   g_sq  = (double*)(ws + 8192);       // 8 x 128 doubles
    float*    AB    = (float*)(ws + 16384);       // 256 f32
    unsigned* flags = (unsigned*)(ws + 17408);    // E/32 words
    size_t    off_s = 17408 + 4 * (size_t)nflag;
    float*    sbuf  = (float*)(ws + off_s);
    size_t    off_h = (off_s + 4 * (size_t)Nn + 255) & ~(size_t)255;
    unsigned* hbuf  = (unsigned*)(ws + off_h);
    const bool use_h = ws_size >= off_h + (size_t)ntiles * 16384;

    int nbN = ((Nn > 1024 ? Nn : 1024) + 255) / 256;
    init_kernel<<<nbN, 256, 0, stream>>>(g_sum, g_sq, sbuf, flags, Nn, nflag);

    int nbO = (nOri + 255) / 256;
    flag_kernel<<<nbO, 256, 0, stream>>>(ori, flags, nOri);

    const int grid_p = ntiles < 1024 ? ntiles : 1024;

    if (use_h)
        pass_kernel<1><<<grid_p, 256, 0, stream>>>(n_feat, W0, rel, b0, row, col, etype,
                                                   AB, W1, b1, g_sum, g_sq, flags, sbuf, out, hbuf, E, ntiles);
    else
        pass_kernel<0><<<grid_p, 256, 0, stream>>>(n_feat, W0, rel, b0, row, col, etype,
                                                   AB, W1, b1, g_sum, g_sq, flags, sbuf, out, hbuf, E, ntiles);

    stats_kernel<<<1, 128, 0, stream>>>(g_sum, g_sq, gamma, beta, AB, E);

    if (use_h) {
        const int grid_h = ntiles < 2048 ? ntiles : 2048;
        pass_kernel<3><<<grid_h, 256, 0, stream>>>(n_feat, W0, rel, b0, row, col, etype,
                                                   AB, W1, b1, g_sum, g_sq, flags, sbuf, out, hbuf, E, ntiles);
    } else {
        pass_kernel<2><<<grid_p, 256, 0, stream>>>(n_feat, W0, rel, b0, row, col, etype,
                                                   AB, W1, b1, g_sum, g_sq, flags, sbuf, out, hbuf, E, ntiles);
    }

    int nbE = (E + 255) / 256;
    norm_kernel<<<nbE, 256, 0, stream>>>(col, sbuf, out, E);
}